// Round 15
// baseline (226.366 us; speedup 1.0000x reference)
//
#include <hip/hip_runtime.h>
#include <hip/hip_bf16.h>
#include <cstdint>
#include <cstddef>

#define D_MODEL 1024
#define NHEADS  16
#define HDIM    64
#define HALFW   32
#define BATCH   4
#define SEQ     4096
#define MROWS   (BATCH*SEQ)

typedef __attribute__((ext_vector_type(8))) short        bf16x8;
typedef __attribute__((ext_vector_type(4))) float        f32x4;
typedef __attribute__((ext_vector_type(16))) float       f32x16;
typedef __attribute__((ext_vector_type(4))) unsigned int u32x4;

typedef const __attribute__((address_space(1))) void gvoid_t;
typedef __attribute__((address_space(3))) void       lvoid_t;

__device__ __forceinline__ unsigned short f2bf(float f) {
    unsigned int u = __float_as_uint(f);
    u += 0x7fffu + ((u >> 16) & 1u);   // RNE
    return (unsigned short)(u >> 16);
}

// XOR swizzle for row-major [R][128] bf16 LDS tiles (256B rows) - attn kernel.
__device__ __forceinline__ int vswz(int row, int bytecol) {
    return (row * 256 + bytecol) ^ (((row ^ (row >> 3)) & 7) << 4);
}

// ------------- single-launch f32->bf16 conversion: x + 4 weight mats ---------
__global__ __launch_bounds__(256)
void cvt_all(const float* __restrict__ x,
             const float* __restrict__ w0, const float* __restrict__ w1,
             const float* __restrict__ w2, const float* __restrict__ w3,
             unsigned short* __restrict__ xb,
             unsigned short* __restrict__ d0, unsigned short* __restrict__ d1,
             unsigned short* __restrict__ d2, unsigned short* __restrict__ d3)
{
    const int bid = blockIdx.x;
    const float* src;
    unsigned short* dst;
    size_t i;
    if (bid < 8192) {
        src = x; dst = xb;
        i = (size_t)bid * 256 + threadIdx.x;
    } else {
        const int r = bid - 8192;
        const int w = r >> 9;
        src = w == 0 ? w0 : w == 1 ? w1 : w == 2 ? w2 : w3;
        dst = w == 0 ? d0 : w == 1 ? d1 : w == 2 ? d2 : d3;
        i = (size_t)(r & 511) * 256 + threadIdx.x;
    }
    float4 a = *(const float4*)(src + i * 8);
    float4 b = *(const float4*)(src + i * 8 + 4);
    u32x4 o;
    o[0] = (unsigned)f2bf(a.x) | ((unsigned)f2bf(a.y) << 16);
    o[1] = (unsigned)f2bf(a.z) | ((unsigned)f2bf(a.w) << 16);
    o[2] = (unsigned)f2bf(b.x) | ((unsigned)f2bf(b.y) << 16);
    o[3] = (unsigned)f2bf(b.z) | ((unsigned)f2bf(b.w) << 16);
    *(u32x4*)(dst + i * 8) = o;
}

// ------- 256x256 wave-staggered bf16 GEMM (B^T), 32x32x16 MFMA ---------------
// Same stagger/staging/vmcnt as r12-14 best; MFMA shape switched 16x16x32 ->
// 32x32x16 (ubench 2382 vs 2075 TF; 2x FLOP/inst halves issue slots).
// Frag: row/col = lane&31, k = (lane>>5)*8+e (16B ds_read). Chunk-pos swizzle
// pos = ((lane>>5) + ((lane&31)>>1))&3 is mt/nt-invariant; ks toggles via ^32.
// C/D (HW-verified m74/m101): col=lane&31, row=(reg&3)+8*(reg>>2)+4*(lane>>5).
template <int NOUT>
__global__ __launch_bounds__(512)
void gemm256(const unsigned short* __restrict__ A,
             const unsigned short* __restrict__ W0,
             const unsigned short* __restrict__ W1,
             const unsigned short* __restrict__ W2,
             const float* __restrict__ b0, const float* __restrict__ b1,
             const float* __restrict__ b2,
             unsigned short* __restrict__ o0, unsigned short* __restrict__ o1,
             unsigned short* __restrict__ o2)
{
    constexpr int K  = 1024;
    constexpr int HT = K / 32;
    constexpr int NWG = 64 * 4 * NOUT;
    __shared__ unsigned short lds[65536];

    const int tid  = threadIdx.x;
    const int wave = tid >> 6, lane = tid & 63;
    const int wr = wave >> 2, wc = wave & 3;
    const bool isX = (wr == 0);

    const int bid = blockIdx.x;
    const int g   = (bid & 7) * (NWG / 8) + (bid >> 3);
    const int rb  = g / (4 * NOUT);
    const int cb  = g % (4 * NOUT);
    const int which = cb >> 2;
    const int bm = rb * 256, bn = (cb & 3) * 256;

    const unsigned short* W = (NOUT == 1 || which == 0) ? W0 : (which == 1 ? W1 : W2);
    const float* bias       = (NOUT == 1 || which == 0) ? b0 : (which == 1 ? b1 : b2);
    unsigned short* obf     = (NOUT == 1 || which == 0) ? o0 : (which == 1 ? o1 : o2);

    f32x16 acc[4][2];
    #pragma unroll
    for (int mt = 0; mt < 4; ++mt)
        #pragma unroll
        for (int nt = 0; nt < 2; ++nt)
            #pragma unroll
            for (int j = 0; j < 16; ++j) acc[mt][nt][j] = 0.0f;

    char* ldsb = (char*)lds;

    const int idx0 = tid, idx1 = tid + 512;
    const int r0 = idx0 >> 2, r1 = idx1 >> 2;
    const int c0 = ((idx0 & 3) - (r0 >> 1)) & 3;
    const int c1 = ((idx1 & 3) - (r1 >> 1)) & 3;
    const size_t sA0 = (size_t)(bm + r0) * K + c0 * 8;
    const size_t sA1 = (size_t)(bm + r1) * K + c1 * 8;
    const size_t sB0 = (size_t)(bn + r0) * K + c0 * 8;
    const size_t sB1 = (size_t)(bn + r1) * K + c1 * 8;
    const int ldsW = wave * 1024;

    auto STAGE = [&](int h, int isA) {
        const int base = (isA ? 0 : 65536) + (h & 3) * 16384 + ldsW;
        const int ke = h * 32;
        const unsigned short* M = isA ? A : W;
        const size_t s0 = isA ? sA0 : sB0;
        const size_t s1 = isA ? sA1 : sB1;
        __builtin_amdgcn_global_load_lds((gvoid_t*)(M + s0 + ke),
            (lvoid_t*)(ldsb + base), 16, 0, 0);
        __builtin_amdgcn_global_load_lds((gvoid_t*)(M + s1 + ke),
            (lvoid_t*)(ldsb + base + 8192), 16, 0, 0);
    };

    const int lr32 = lane & 31, hk = lane >> 5;
    const int pos0 = ((hk + (lr32 >> 1)) & 3) << 4;            // ks=0 chunk pos
    const int abase = (wr * 128 + lr32) * 64 + pos0;           // + mt*2048; ks1 = ^32
    const int bbase = 65536 + (wc * 64 + lr32) * 64 + pos0;    // + nt*2048; ks1 = ^32

    STAGE(0, 1); STAGE(0, 0); STAGE(1, 1); STAGE(1, 0); STAGE(2, 1); STAGE(2, 0);
    asm volatile("s_waitcnt vmcnt(8)" ::: "memory");
    __builtin_amdgcn_s_barrier();

    bf16x8 fa[4][2], fb[2][2];

    #pragma unroll 1
    for (int hp = 0; hp < HT; ++hp) {
        const int so = (hp & 3) * 16384;
        // ---------------- S1: X reads(hp) | Y MFMA(hp-1) --------------------
        if (isX) {
            #pragma unroll
            for (int mt = 0; mt < 4; ++mt) {
                const int ao = so + abase + mt * 2048;
                fa[mt][0] = *(const bf16x8*)(ldsb + ao);
                fa[mt][1] = *(const bf16x8*)(ldsb + (ao ^ 32));
            }
            #pragma unroll
            for (int nt = 0; nt < 2; ++nt) {
                const int bo = so + bbase + nt * 2048;
                fb[nt][0] = *(const bf16x8*)(ldsb + bo);
                fb[nt][1] = *(const bf16x8*)(ldsb + (bo ^ 32));
            }
        } else if (hp > 0) {
            asm volatile("s_waitcnt lgkmcnt(0)" ::: "memory");
            __builtin_amdgcn_sched_barrier(0);          // rule #18
            __builtin_amdgcn_s_setprio(1);
            #pragma unroll
            for (int mt = 0; mt < 4; ++mt)
                #pragma unroll
                for (int nt = 0; nt < 2; ++nt)
                    #pragma unroll
                    for (int ks = 0; ks < 2; ++ks)
                        acc[mt][nt] = __builtin_amdgcn_mfma_f32_32x32x16_bf16(
                            fa[mt][ks], fb[nt][ks], acc[mt][nt], 0, 0, 0);
            __builtin_amdgcn_s_setprio(0);
        }
        __builtin_amdgcn_s_barrier();
        // ---------------- S2: stage(hp+3); X MFMA(hp) | Y reads(hp) ---------
        if (hp + 3 < HT) { STAGE(hp + 3, 1); STAGE(hp + 3, 0); }
        if (isX) {
            asm volatile("s_waitcnt lgkmcnt(0)" ::: "memory");
            __builtin_amdgcn_sched_barrier(0);          // rule #18
            __builtin_amdgcn_s_setprio(1);
            #pragma unroll
            for (int mt = 0; mt < 4; ++mt)
                #pragma unroll
                for (int nt = 0; nt < 2; ++nt)
                    #pragma unroll
                    for (int ks = 0; ks < 2; ++ks)
                        acc[mt][nt] = __builtin_amdgcn_mfma_f32_32x32x16_bf16(
                            fa[mt][ks], fb[nt][ks], acc[mt][nt], 0, 0, 0);
            __builtin_amdgcn_s_setprio(0);
        } else {
            #pragma unroll
            for (int mt = 0; mt < 4; ++mt) {
                const int ao = so + abase + mt * 2048;
                fa[mt][0] = *(const bf16x8*)(ldsb + ao);
                fa[mt][1] = *(const bf16x8*)(ldsb + (ao ^ 32));
            }
            #pragma unroll
            for (int nt = 0; nt < 2; ++nt) {
                const int bo = so + bbase + nt * 2048;
                fb[nt][0] = *(const bf16x8*)(ldsb + bo);
                fb[nt][1] = *(const bf16x8*)(ldsb + (bo ^ 32));
            }
        }
        if (hp <= HT - 4)      { asm volatile("s_waitcnt vmcnt(8)" ::: "memory"); }
        else if (hp == HT - 3) { asm volatile("s_waitcnt vmcnt(4)" ::: "memory"); }
        else                   { asm volatile("s_waitcnt vmcnt(0)" ::: "memory"); }
        __builtin_amdgcn_s_barrier();
    }
    if (!isX) {
        asm volatile("s_waitcnt lgkmcnt(0)" ::: "memory");
        __builtin_amdgcn_sched_barrier(0);              // rule #18
        #pragma unroll
        for (int mt = 0; mt < 4; ++mt)
            #pragma unroll
            for (int nt = 0; nt < 2; ++nt)
                #pragma unroll
                for (int ks = 0; ks < 2; ++ks)
                    acc[mt][nt] = __builtin_amdgcn_mfma_f32_32x32x16_bf16(
                        fa[mt][ks], fb[nt][ks], acc[mt][nt], 0, 0, 0);
    }

    // epilogue: C/D col=lane&31, row=(reg&3)+8*(reg>>2)+4*hk; nt inner -> 128B
    float bvv[2];
    #pragma unroll
    for (int nt = 0; nt < 2; ++nt) bvv[nt] = bias[bn + wc * 64 + nt * 32 + lr32];
    #pragma unroll
    for (int mt = 0; mt < 4; ++mt) {
        #pragma unroll
        for (int reg = 0; reg < 16; ++reg) {
            const int row = bm + wr * 128 + mt * 32 + (reg & 3) + 8 * (reg >> 2) + 4 * hk;
            #pragma unroll
            for (int nt = 0; nt < 2; ++nt) {
                const int col = bn + wc * 64 + nt * 32 + lr32;
                obf[(size_t)row * 1024 + col] = f2bf(acc[mt][nt][reg] + bvv[nt]);
            }
        }
    }
}

// ---- O-proj: 256x128 double-buffered bf16 GEMM, 4 waves, 2 blocks/CU --------
__global__ __launch_bounds__(256, 2)
void gemm_o(const unsigned short* __restrict__ A,
            const unsigned short* __restrict__ W0,
            const float* __restrict__ b0, float* __restrict__ of32)
{
    constexpr int K  = 1024;
    constexpr int HT = K / 32;
    __shared__ unsigned short lds[2 * 12288];

    const int tid  = threadIdx.x;
    const int wave = tid >> 6, lane = tid & 63;
    const int wr = wave >> 1, wc = wave & 1;

    const int bid = blockIdx.x;
    const int g   = (bid & 7) * 64 + (bid >> 3);
    const int rb  = g >> 3;
    const int cbg = g & 7;
    const int bm = rb * 256, bn = cbg * 128;

    f32x4 acc[8][4];
    #pragma unroll
    for (int m = 0; m < 8; ++m)
        #pragma unroll
        for (int n = 0; n < 4; ++n)
            #pragma unroll
            for (int j = 0; j < 4; ++j) acc[m][n][j] = 0.0f;

    char* ldsb = (char*)lds;

    const int ra  = tid >> 2;
    const int ks  = ((tid & 3) - (ra >> 1)) & 3;
    const size_t sA[4] = { (size_t)(bm + ra) * K + ks * 8,
                           (size_t)(bm + ra + 64)  * K + ks * 8,
                           (size_t)(bm + ra + 128) * K + ks * 8,
                           (size_t)(bm + ra + 192) * K + ks * 8 };
    const size_t sB[2] = { (size_t)(bn + ra) * K + ks * 8,
                           (size_t)(bn + ra + 64)  * K + ks * 8 };
    const int ldsW = wave * 1024;

    auto STAGE = [&](int h) {
        const int slot = (h & 1) * 24576;
        const int ke = h * 32;
        #pragma unroll
        for (int i = 0; i < 4; ++i)
            __builtin_amdgcn_global_load_lds((gvoid_t*)(A + sA[i] + ke),
                (lvoid_t*)(ldsb + slot + ldsW + i * 4096), 16, 0, 0);
        #pragma unroll
        for (int i = 0; i < 2; ++i)
            __builtin_amdgcn_global_load_lds((gvoid_t*)(W0 + sB[i] + ke),
                (lvoid_t*)(ldsb + slot + 16384 + ldsW + i * 4096), 16, 0, 0);
    };

    const int lr = lane & 15;
    const int pp = (((lane >> 4) + (lr >> 1)) & 3) << 4;
    const int abase = (wr * 128 + lr) * 64 + pp;
    const int bbase = 16384 + (wc * 64 + lr) * 64 + pp;

    STAGE(0);
    __syncthreads();

    #pragma unroll 1
    for (int h = 0; h < HT; ++h) {
        const char* sl = ldsb + (h & 1) * 24576;
        if (h + 1 < HT) STAGE(h + 1);
        bf16x8 fa[8], fb[4];
        #pragma unroll
        for (int m = 0; m < 8; ++m) fa[m] = *(const bf16x8*)(sl + abase + m * 1024);
        #pragma unroll
        for (int n = 0; n < 4; ++n) fb[n] = *(const bf16x8*)(sl + bbase + n * 1024);
        #pragma unroll
        for (int m = 0; m < 8; ++m)
            #pragma unroll
            for (int n = 0; n < 4; ++n)
                acc[m][n] = __builtin_amdgcn_mfma_f32_16x16x32_bf16(fa[m], fb[n], acc[m][n], 0, 0, 0);
        __syncthreads();
    }

    float bvv[4];
    #pragma unroll
    for (int n = 0; n < 4; ++n) bvv[n] = b0[bn + wc * 64 + n * 16 + lr];
    #pragma unroll
    for (int m = 0; m < 8; ++m) {
        #pragma unroll
        for (int j = 0; j < 4; ++j) {
            const int row = bm + wr * 128 + m * 16 + (lane >> 4) * 4 + j;
            #pragma unroll
            for (int n = 0; n < 4; ++n) {
                const int col = bn + wc * 64 + n * 16 + lr;
                of32[(size_t)row * 1024 + col] = acc[m][n][j] + bvv[n];
            }
        }
    }
}

// -------- banded attention v3: 32KB LDS (Vt+Ps only), Q/K direct-global ------
__global__ __launch_bounds__(256)
void attn_band(const unsigned short* __restrict__ Q,
               const unsigned short* __restrict__ Kk,
               const unsigned short* __restrict__ V,
               unsigned short* __restrict__ Ctx)
{
    __shared__ unsigned short Vt[64 * 128];   // [hd][key], XOR-swizzled
    __shared__ unsigned short Ps[64 * 128];   // [q][key],  XOR-swizzled

    const int qt = blockIdx.x, h = blockIdx.y, b = blockIdx.z;
    const int qbase  = qt * 64;
    const int kstart = qbase - HALFW;
    const int tid = threadIdx.x, wave = tid >> 6, lane = tid & 63;

    const size_t base = (size_t)b * SEQ * D_MODEL + (size_t)h * HDIM;
    const unsigned short* Qb = Q  + base;
    const unsigned short* Kb = Kk + base;
    const unsigned short* Vb = V  + base;
    unsigned short*       Cb = Ctx + base;

    for (int c = tid; c < 512; c += 256) {
        const int p = c >> 3, dch = c & 7;
        const int k0 = kstart + 2 * p, k1 = k0 + 1;
        u32x4 v0, v1;
        if (k0 >= 0 && k0 < SEQ) {
            v0 = *(const u32x4*)(Vb + (size_t)k0 * D_MODEL + dch * 8);
        } else {
            for (int j = 0; j < 4; ++j) v0[j] = 0u;
        }
        if (k1 >= 0 && k1 < SEQ) {
            v1 = *(const u32x4*)(Vb + (size_t)k1 * D_MODEL + dch * 8);
        } else {
            for (int j = 0; j < 4; ++j) v1[j] = 0u;
        }
        #pragma unroll
        for (int j = 0; j < 8; ++j) {
            const int d = dch * 8 + j;
            const unsigned lo = (v0[j >> 1] >> ((j & 1) * 16)) & 0xffffu;
            const unsigned hi = (v1[j >> 1] >> ((j & 1) * 16)) & 0xffffu;
            *(unsigned*)((char*)Vt + vswz(d, 4 * p)) = lo | (hi << 16);
        }
    }
    __syncthreads();

    f32x4 sc[8];
    #pragma unroll
    for (int c = 0; c < 8; ++c)
        #pragma unroll
        for (int j = 0; j < 4; ++j) sc[c][j] = 0.0f;

    const int fcol = (lane >> 4) * 8;
    bf16x8 aq[2];
    #pragma unroll
    for (int kc = 0; kc < 2; ++kc)
        aq[kc] = *(const bf16x8*)(Qb + (size_t)(qbase + wave * 16 + (lane & 15)) * D_MODEL
                                     + kc * 32 + fcol);
    #pragma unroll
    for (int c = 0; c < 8; ++c) {
        const long krow = (long)kstart + c * 16 + (lane & 15);
        const unsigned short* kp = Kb + krow * (long)D_MODEL + fcol;
        #pragma unroll
        for (int kc = 0; kc < 2; ++kc) {
            bf16x8 bk_ = *(const bf16x8*)(kp + kc * 32);
            sc[c] = __builtin_amdgcn_mfma_f32_16x16x32_bf16(aq[kc], bk_, sc[c], 0, 0, 0);
        }
    }

    const int grp = lane >> 4, colk = lane & 15;
    float rowmax[4] = {-1e30f, -1e30f, -1e30f, -1e30f};
    #pragma unroll
    for (int c = 0; c < 8; ++c) {
        const int kpos = kstart + c * 16 + colk;
        #pragma unroll
        for (int j = 0; j < 4; ++j) {
            const int qpos = qbase + wave * 16 + grp * 4 + j;
            const int rel = kpos - qpos;
            const bool valid = (kpos >= 0) && (kpos < SEQ) && (rel >= -HALFW) && (rel <= HALFW);
            const float v = valid ? sc[c][j] * 0.125f : -1e30f;
            sc[c][j] = v;
            rowmax[j] = fmaxf(rowmax[j], v);
        }
    }
    #pragma unroll
    for (int j = 0; j < 4; ++j)
        #pragma unroll
        for (int m = 1; m < 16; m <<= 1)
            rowmax[j] = fmaxf(rowmax[j], __shfl_xor(rowmax[j], m, 64));

    float rowsum[4] = {0.f, 0.f, 0.f, 0.f};
    #pragma unroll
    for (int c = 0; c < 8; ++c)
        #pragma unroll
        for (int j = 0; j < 4; ++j) {
            const float p = __expf(sc[c][j] - rowmax[j]);
            sc[c][j] = p;
            rowsum[j] += p;
        }
    #pragma unroll
    for (int j = 0; j < 4; ++j)
        #pragma unroll
        for (int m = 1; m < 16; m <<= 1)
            rowsum[j] += __shfl_xor(rowsum[j], m, 64);

    #pragma unroll
    for (int c = 0; c < 8; ++c)
        #pragma unroll
        for (int j = 0; j < 4; ++j)
            *(unsigned short*)((char*)Ps + vswz(wave * 16 + grp * 4 + j, (c * 16 + colk) * 2))
                = f2bf(sc[c][j]);

    f32x4 o[4];
    #pragma unroll
    for (int n = 0; n < 4; ++n)
        #pragma unroll
        for (int j = 0; j < 4; ++j) o[n][j] = 0.0f;
    #pragma unroll
    for (int kc = 0; kc < 4; ++kc) {
        bf16x8 pa = *(const bf16x8*)((const char*)Ps +
                        vswz(wave * 16 + (lane & 15), kc * 64 + (lane >> 4) * 16));
        #pragma unroll
        for (int n = 0; n < 4; ++n) {
            bf16x8 bv_ = *(const bf16x8*)((const char*)Vt +
                            vswz(n * 16 + (lane & 15), kc * 64 + (lane >> 4) * 16));
            o[n] = __builtin_amdgcn_mfma_f32_16x16x32_bf16(pa, bv_, o[n], 0, 0, 0);
        }
    }

    float rinv[4];
    #pragma unroll
    for (int j = 0; j < 4; ++j) rinv[j] = 1.0f / rowsum[j];
    #pragma unroll
    for (int n = 0; n < 4; ++n)
        #pragma unroll
        for (int j = 0; j < 4; ++j) {
            const int q = qbase + wave * 16 + grp * 4 + j;
            Cb[(size_t)q * D_MODEL + n * 16 + colk] = f2bf(o[n][j] * rinv[j]);
        }
}

// ------------------------------------------------------------------------------
extern "C" void kernel_launch(void* const* d_in, const int* in_sizes, int n_in,
                              void* d_out, int out_size, void* d_ws, size_t ws_size,
                              hipStream_t stream)
{
    (void)in_sizes; (void)n_in; (void)out_size; (void)ws_size;
    const float* x  = (const float*)d_in[0];
    const float* Wq = (const float*)d_in[1];
    const float* bq = (const float*)d_in[2];
    const float* Wk = (const float*)d_in[3];
    const float* bk = (const float*)d_in[4];
    const float* Wv = (const float*)d_in[5];
    const float* bv = (const float*)d_in[6];
    const float* Wo = (const float*)d_in[7];
    const float* bo = (const float*)d_in[8];
    float* out = (float*)d_out;

    char* ws = (char*)d_ws;
    unsigned short* xb  = (unsigned short*)ws;
    unsigned short* wqb = (unsigned short*)(ws + 33554432);
    unsigned short* wkb = wqb + 1048576;
    unsigned short* wvb = wkb + 1048576;
    unsigned short* wob = wvb + 1048576;
    unsigned short* qb  = wob + 1048576;
    unsigned short* kb  = qb + (size_t)MROWS * D_MODEL;
    unsigned short* vb  = kb + (size_t)MROWS * D_MODEL;
    unsigned short* ctxb = xb;   // alias: x no longer needed after QKV GEMM

    cvt_all<<<dim3(8192 + 4 * 512), 256, 0, stream>>>(
        x, Wq, Wk, Wv, Wo, xb, wqb, wkb, wvb, wob);

    // fused QKV: 64 row-blocks x 12 col-blocks (256^2 tiles), 32x32 MFMA
    gemm256<3><<<dim3(768), 512, 0, stream>>>(
        xb, wqb, wkb, wvb, bq, bk, bv, qb, kb, vb);

    attn_band<<<dim3(SEQ / 64, NHEADS, BATCH), 256, 0, stream>>>(qb, kb, vb, ctxb);

    // O-proj: 64 row-blocks x 8 col-blocks (256x128 tiles), 2 blocks/CU
    gemm_o<<<dim3(512), 256, 0, stream>>>(ctxb, wob, bo, out);
}

// Round 16
// 220.954 us; speedup vs baseline: 1.0245x; 1.0245x over previous
//
#include <hip/hip_runtime.h>
#include <hip/hip_bf16.h>
#include <cstdint>
#include <cstddef>

#define D_MODEL 1024
#define NHEADS  16
#define HDIM    64
#define HALFW   32
#define BATCH   4
#define SEQ     4096
#define MROWS   (BATCH*SEQ)

typedef __attribute__((ext_vector_type(8))) short        bf16x8;
typedef __attribute__((ext_vector_type(4))) float        f32x4;
typedef __attribute__((ext_vector_type(4))) unsigned int u32x4;

typedef const __attribute__((address_space(1))) void gvoid_t;
typedef __attribute__((address_space(3))) void       lvoid_t;

__device__ __forceinline__ unsigned short f2bf(float f) {
    unsigned int u = __float_as_uint(f);
    u += 0x7fffu + ((u >> 16) & 1u);   // RNE
    return (unsigned short)(u >> 16);
}

// XOR swizzle for row-major [R][128] bf16 LDS tiles (256B rows) - attn kernel.
__device__ __forceinline__ int vswz(int row, int bytecol) {
    return (row * 256 + bytecol) ^ (((row ^ (row >> 3)) & 7) << 4);
}

// ------------- single-launch f32->bf16 conversion: x + 4 weight mats ---------
__global__ __launch_bounds__(256)
void cvt_all(const float* __restrict__ x,
             const float* __restrict__ w0, const float* __restrict__ w1,
             const float* __restrict__ w2, const float* __restrict__ w3,
             unsigned short* __restrict__ xb,
             unsigned short* __restrict__ d0, unsigned short* __restrict__ d1,
             unsigned short* __restrict__ d2, unsigned short* __restrict__ d3)
{
    const int bid = blockIdx.x;
    const float* src;
    unsigned short* dst;
    size_t i;
    if (bid < 8192) {
        src = x; dst = xb;
        i = (size_t)bid * 256 + threadIdx.x;
    } else {
        const int r = bid - 8192;
        const int w = r >> 9;
        src = w == 0 ? w0 : w == 1 ? w1 : w == 2 ? w2 : w3;
        dst = w == 0 ? d0 : w == 1 ? d1 : w == 2 ? d2 : d3;
        i = (size_t)(r & 511) * 256 + threadIdx.x;
    }
    float4 a = *(const float4*)(src + i * 8);
    float4 b = *(const float4*)(src + i * 8 + 4);
    u32x4 o;
    o[0] = (unsigned)f2bf(a.x) | ((unsigned)f2bf(a.y) << 16);
    o[1] = (unsigned)f2bf(a.z) | ((unsigned)f2bf(a.w) << 16);
    o[2] = (unsigned)f2bf(b.x) | ((unsigned)f2bf(b.y) << 16);
    o[3] = (unsigned)f2bf(b.z) | ((unsigned)f2bf(b.w) << 16);
    *(u32x4*)(dst + i * 8) = o;
}

// ------- 256x256 wave-staggered bf16 GEMM (B^T), 8 waves, half-tile=32k ------
// Best-measured config (r13: QKV 110.4us, MfmaUtil 39.5%, conflicts 0).
//   S1: X ds_read(hp)               | Y MFMA(hp-1)
//   S2: stage(hp+3) A+B; X MFMA(hp) | Y ds_read(hp); vmcnt ladder 8/4/0
// Conflict-free chunk swizzle: chunk c of row r at position (c+(r>>1))&3.
template <int NOUT, int F32OUT>
__global__ __launch_bounds__(512)
void gemm256(const unsigned short* __restrict__ A,
             const unsigned short* __restrict__ W0,
             const unsigned short* __restrict__ W1,
             const unsigned short* __restrict__ W2,
             const float* __restrict__ b0, const float* __restrict__ b1,
             const float* __restrict__ b2,
             unsigned short* __restrict__ o0, unsigned short* __restrict__ o1,
             unsigned short* __restrict__ o2, float* __restrict__ of32)
{
    constexpr int K  = 1024;
    constexpr int HT = K / 32;
    constexpr int NWG = 64 * 4 * NOUT;
    __shared__ unsigned short lds[65536];

    const int tid  = threadIdx.x;
    const int wave = tid >> 6, lane = tid & 63;
    const int wr = wave >> 2, wc = wave & 3;
    const bool isX = (wr == 0);

    const int bid = blockIdx.x;
    const int g   = (bid & 7) * (NWG / 8) + (bid >> 3);
    const int rb  = g / (4 * NOUT);
    const int cb  = g % (4 * NOUT);
    const int which = cb >> 2;
    const int bm = rb * 256, bn = (cb & 3) * 256;

    const unsigned short* W = (NOUT == 1 || which == 0) ? W0 : (which == 1 ? W1 : W2);
    const float* bias       = (NOUT == 1 || which == 0) ? b0 : (which == 1 ? b1 : b2);
    unsigned short* obf     = (NOUT == 1 || which == 0) ? o0 : (which == 1 ? o1 : o2);

    f32x4 acc[8][4];
    #pragma unroll
    for (int m = 0; m < 8; ++m)
        #pragma unroll
        for (int n = 0; n < 4; ++n)
            #pragma unroll
            for (int j = 0; j < 4; ++j) acc[m][n][j] = 0.0f;

    char* ldsb = (char*)lds;

    const int idx0 = tid, idx1 = tid + 512;
    const int r0 = idx0 >> 2, r1 = idx1 >> 2;
    const int c0 = ((idx0 & 3) - (r0 >> 1)) & 3;
    const int c1 = ((idx1 & 3) - (r1 >> 1)) & 3;
    const size_t sA0 = (size_t)(bm + r0) * K + c0 * 8;
    const size_t sA1 = (size_t)(bm + r1) * K + c1 * 8;
    const size_t sB0 = (size_t)(bn + r0) * K + c0 * 8;
    const size_t sB1 = (size_t)(bn + r1) * K + c1 * 8;
    const int ldsW = wave * 1024;

    auto STAGE = [&](int h, int isA) {
        const int base = (isA ? 0 : 65536) + (h & 3) * 16384 + ldsW;
        const int ke = h * 32;
        const unsigned short* M = isA ? A : W;
        const size_t s0 = isA ? sA0 : sB0;
        const size_t s1 = isA ? sA1 : sB1;
        __builtin_amdgcn_global_load_lds((gvoid_t*)(M + s0 + ke),
            (lvoid_t*)(ldsb + base), 16, 0, 0);
        __builtin_amdgcn_global_load_lds((gvoid_t*)(M + s1 + ke),
            (lvoid_t*)(ldsb + base + 8192), 16, 0, 0);
    };

    const int lr = lane & 15;
    const int pp = (((lane >> 4) + (lr >> 1)) & 3) << 4;
    const int abase = (wr * 128 + lr) * 64 + pp;
    const int bbase = 65536 + (wc * 64 + lr) * 64 + pp;

    STAGE(0, 1); STAGE(0, 0); STAGE(1, 1); STAGE(1, 0); STAGE(2, 1); STAGE(2, 0);
    asm volatile("s_waitcnt vmcnt(8)" ::: "memory");
    __builtin_amdgcn_s_barrier();

    bf16x8 fa[8], fb[4];

    #pragma unroll 1
    for (int hp = 0; hp < HT; ++hp) {
        const int so = (hp & 3) * 16384;
        // ---------------- S1: X reads(hp) | Y MFMA(hp-1) --------------------
        if (isX) {
            #pragma unroll
            for (int m = 0; m < 8; ++m) fa[m] = *(const bf16x8*)(ldsb + so + abase + m * 1024);
            #pragma unroll
            for (int n = 0; n < 4; ++n) fb[n] = *(const bf16x8*)(ldsb + so + bbase + n * 1024);
        } else if (hp > 0) {
            asm volatile("s_waitcnt lgkmcnt(0)" ::: "memory");
            __builtin_amdgcn_sched_barrier(0);          // rule #18
            __builtin_amdgcn_s_setprio(1);
            #pragma unroll
            for (int m = 0; m < 8; ++m)
                #pragma unroll
                for (int n = 0; n < 4; ++n)
                    acc[m][n] = __builtin_amdgcn_mfma_f32_16x16x32_bf16(fa[m], fb[n], acc[m][n], 0, 0, 0);
            __builtin_amdgcn_s_setprio(0);
        }
        __builtin_amdgcn_s_barrier();
        // ---------------- S2: stage(hp+3); X MFMA(hp) | Y reads(hp) ---------
        if (hp + 3 < HT) { STAGE(hp + 3, 1); STAGE(hp + 3, 0); }
        if (isX) {
            asm volatile("s_waitcnt lgkmcnt(0)" ::: "memory");
            __builtin_amdgcn_sched_barrier(0);          // rule #18
            __builtin_amdgcn_s_setprio(1);
            #pragma unroll
            for (int m = 0; m < 8; ++m)
                #pragma unroll
                for (int n = 0; n < 4; ++n)
                    acc[m][n] = __builtin_amdgcn_mfma_f32_16x16x32_bf16(fa[m], fb[n], acc[m][n], 0, 0, 0);
            __builtin_amdgcn_s_setprio(0);
        } else {
            #pragma unroll
            for (int m = 0; m < 8; ++m) fa[m] = *(const bf16x8*)(ldsb + so + abase + m * 1024);
            #pragma unroll
            for (int n = 0; n < 4; ++n) fb[n] = *(const bf16x8*)(ldsb + so + bbase + n * 1024);
        }
        if (hp <= HT - 4)      { asm volatile("s_waitcnt vmcnt(8)" ::: "memory"); }
        else if (hp == HT - 3) { asm volatile("s_waitcnt vmcnt(4)" ::: "memory"); }
        else                   { asm volatile("s_waitcnt vmcnt(0)" ::: "memory"); }
        __builtin_amdgcn_s_barrier();
    }
    if (!isX) {
        asm volatile("s_waitcnt lgkmcnt(0)" ::: "memory");
        __builtin_amdgcn_sched_barrier(0);              // rule #18
        #pragma unroll
        for (int m = 0; m < 8; ++m)
            #pragma unroll
            for (int n = 0; n < 4; ++n)
                acc[m][n] = __builtin_amdgcn_mfma_f32_16x16x32_bf16(fa[m], fb[n], acc[m][n], 0, 0, 0);
    }

    // epilogue: bias + store, n innermost (full 128B lines per 16-lane group)
    float bvv[4];
    #pragma unroll
    for (int n = 0; n < 4; ++n) bvv[n] = bias[bn + wc * 64 + n * 16 + lr];
    #pragma unroll
    for (int m = 0; m < 8; ++m) {
        #pragma unroll
        for (int j = 0; j < 4; ++j) {
            const int row = bm + wr * 128 + m * 16 + (lane >> 4) * 4 + j;
            #pragma unroll
            for (int n = 0; n < 4; ++n) {
                const int col = bn + wc * 64 + n * 16 + lr;
                const float v = acc[m][n][j] + bvv[n];
                if (F32OUT) of32[(size_t)row * 1024 + col] = v;
                else        obf[(size_t)row * 1024 + col]  = f2bf(v);
            }
        }
    }
}

// -------- banded attention v3: 32KB LDS (Vt+Ps only), Q/K direct-global ------
__global__ __launch_bounds__(256)
void attn_band(const unsigned short* __restrict__ Q,
               const unsigned short* __restrict__ Kk,
               const unsigned short* __restrict__ V,
               unsigned short* __restrict__ Ctx)
{
    __shared__ unsigned short Vt[64 * 128];   // [hd][key], XOR-swizzled
    __shared__ unsigned short Ps[64 * 128];   // [q][key],  XOR-swizzled

    const int qt = blockIdx.x, h = blockIdx.y, b = blockIdx.z;
    const int qbase  = qt * 64;
    const int kstart = qbase - HALFW;
    const int tid = threadIdx.x, wave = tid >> 6, lane = tid & 63;

    const size_t base = (size_t)b * SEQ * D_MODEL + (size_t)h * HDIM;
    const unsigned short* Qb = Q  + base;
    const unsigned short* Kb = Kk + base;
    const unsigned short* Vb = V  + base;
    unsigned short*       Cb = Ctx + base;

    for (int c = tid; c < 512; c += 256) {
        const int p = c >> 3, dch = c & 7;
        const int k0 = kstart + 2 * p, k1 = k0 + 1;
        u32x4 v0, v1;
        if (k0 >= 0 && k0 < SEQ) {
            v0 = *(const u32x4*)(Vb + (size_t)k0 * D_MODEL + dch * 8);
        } else {
            for (int j = 0; j < 4; ++j) v0[j] = 0u;
        }
        if (k1 >= 0 && k1 < SEQ) {
            v1 = *(const u32x4*)(Vb + (size_t)k1 * D_MODEL + dch * 8);
        } else {
            for (int j = 0; j < 4; ++j) v1[j] = 0u;
        }
        #pragma unroll
        for (int j = 0; j < 8; ++j) {
            const int d = dch * 8 + j;
            const unsigned lo = (v0[j >> 1] >> ((j & 1) * 16)) & 0xffffu;
            const unsigned hi = (v1[j >> 1] >> ((j & 1) * 16)) & 0xffffu;
            *(unsigned*)((char*)Vt + vswz(d, 4 * p)) = lo | (hi << 16);
        }
    }
    __syncthreads();

    f32x4 sc[8];
    #pragma unroll
    for (int c = 0; c < 8; ++c)
        #pragma unroll
        for (int j = 0; j < 4; ++j) sc[c][j] = 0.0f;

    const int fcol = (lane >> 4) * 8;
    bf16x8 aq[2];
    #pragma unroll
    for (int kc = 0; kc < 2; ++kc)
        aq[kc] = *(const bf16x8*)(Qb + (size_t)(qbase + wave * 16 + (lane & 15)) * D_MODEL
                                     + kc * 32 + fcol);
    #pragma unroll
    for (int c = 0; c < 8; ++c) {
        const long krow = (long)kstart + c * 16 + (lane & 15);
        const unsigned short* kp = Kb + krow * (long)D_MODEL + fcol;
        #pragma unroll
        for (int kc = 0; kc < 2; ++kc) {
            bf16x8 bk_ = *(const bf16x8*)(kp + kc * 32);
            sc[c] = __builtin_amdgcn_mfma_f32_16x16x32_bf16(aq[kc], bk_, sc[c], 0, 0, 0);
        }
    }

    const int grp = lane >> 4, colk = lane & 15;
    float rowmax[4] = {-1e30f, -1e30f, -1e30f, -1e30f};
    #pragma unroll
    for (int c = 0; c < 8; ++c) {
        const int kpos = kstart + c * 16 + colk;
        #pragma unroll
        for (int j = 0; j < 4; ++j) {
            const int qpos = qbase + wave * 16 + grp * 4 + j;
            const int rel = kpos - qpos;
            const bool valid = (kpos >= 0) && (kpos < SEQ) && (rel >= -HALFW) && (rel <= HALFW);
            const float v = valid ? sc[c][j] * 0.125f : -1e30f;
            sc[c][j] = v;
            rowmax[j] = fmaxf(rowmax[j], v);
        }
    }
    #pragma unroll
    for (int j = 0; j < 4; ++j)
        #pragma unroll
        for (int m = 1; m < 16; m <<= 1)
            rowmax[j] = fmaxf(rowmax[j], __shfl_xor(rowmax[j], m, 64));

    float rowsum[4] = {0.f, 0.f, 0.f, 0.f};
    #pragma unroll
    for (int c = 0; c < 8; ++c)
        #pragma unroll
        for (int j = 0; j < 4; ++j) {
            const float p = __expf(sc[c][j] - rowmax[j]);
            sc[c][j] = p;
            rowsum[j] += p;
        }
    #pragma unroll
    for (int j = 0; j < 4; ++j)
        #pragma unroll
        for (int m = 1; m < 16; m <<= 1)
            rowsum[j] += __shfl_xor(rowsum[j], m, 64);

    #pragma unroll
    for (int c = 0; c < 8; ++c)
        #pragma unroll
        for (int j = 0; j < 4; ++j)
            *(unsigned short*)((char*)Ps + vswz(wave * 16 + grp * 4 + j, (c * 16 + colk) * 2))
                = f2bf(sc[c][j]);

    f32x4 o[4];
    #pragma unroll
    for (int n = 0; n < 4; ++n)
        #pragma unroll
        for (int j = 0; j < 4; ++j) o[n][j] = 0.0f;
    #pragma unroll
    for (int kc = 0; kc < 4; ++kc) {
        bf16x8 pa = *(const bf16x8*)((const char*)Ps +
                        vswz(wave * 16 + (lane & 15), kc * 64 + (lane >> 4) * 16));
        #pragma unroll
        for (int n = 0; n < 4; ++n) {
            bf16x8 bv_ = *(const bf16x8*)((const char*)Vt +
                            vswz(n * 16 + (lane & 15), kc * 64 + (lane >> 4) * 16));
            o[n] = __builtin_amdgcn_mfma_f32_16x16x32_bf16(pa, bv_, o[n], 0, 0, 0);
        }
    }

    float rinv[4];
    #pragma unroll
    for (int j = 0; j < 4; ++j) rinv[j] = 1.0f / rowsum[j];
    #pragma unroll
    for (int n = 0; n < 4; ++n)
        #pragma unroll
        for (int j = 0; j < 4; ++j) {
            const int q = qbase + wave * 16 + grp * 4 + j;
            Cb[(size_t)q * D_MODEL + n * 16 + colk] = f2bf(o[n][j] * rinv[j]);
        }
}

// ------------------------------------------------------------------------------
extern "C" void kernel_launch(void* const* d_in, const int* in_sizes, int n_in,
                              void* d_out, int out_size, void* d_ws, size_t ws_size,
                              hipStream_t stream)
{
    (void)in_sizes; (void)n_in; (void)out_size; (void)ws_size;
    const float* x  = (const float*)d_in[0];
    const float* Wq = (const float*)d_in[1];
    const float* bq = (const float*)d_in[2];
    const float* Wk = (const float*)d_in[3];
    const float* bk = (const float*)d_in[4];
    const float* Wv = (const float*)d_in[5];
    const float* bv = (const float*)d_in[6];
    const float* Wo = (const float*)d_in[7];
    const float* bo = (const float*)d_in[8];
    float* out = (float*)d_out;

    char* ws = (char*)d_ws;
    unsigned short* xb  = (unsigned short*)ws;
    unsigned short* wqb = (unsigned short*)(ws + 33554432);
    unsigned short* wkb = wqb + 1048576;
    unsigned short* wvb = wkb + 1048576;
    unsigned short* wob = wvb + 1048576;
    unsigned short* qb  = wob + 1048576;
    unsigned short* kb  = qb + (size_t)MROWS * D_MODEL;
    unsigned short* vb  = kb + (size_t)MROWS * D_MODEL;
    unsigned short* ctxb = xb;   // alias: x no longer needed after QKV GEMM

    cvt_all<<<dim3(8192 + 4 * 512), 256, 0, stream>>>(
        x, Wq, Wk, Wv, Wo, xb, wqb, wkb, wvb, wob);

    // fused QKV: 64 row-blocks x 12 col-blocks (256^2 tiles), staggered waves
    gemm256<3, 0><<<dim3(768), 512, 0, stream>>>(
        xb, wqb, wkb, wvb, bq, bk, bv, qb, kb, vb, nullptr);

    attn_band<<<dim3(SEQ / 64, NHEADS, BATCH), 256, 0, stream>>>(qb, kb, vb, ctxb);

    gemm256<1, 1><<<dim3(256), 512, 0, stream>>>(
        ctxb, wob, wob, wob, bo, bo, bo, nullptr, nullptr, nullptr, out);
}